// Round 3
// baseline (1267.130 us; speedup 1.0000x reference)
//
#include <hip/hip_runtime.h>
#include <hip/hip_bf16.h>
#include <math.h>

#define NFEAT 128
#define NNODE 256
#define NHEAD 8
#define DHEAD 16
#define NLAYER 9

typedef unsigned short u16;
typedef __attribute__((ext_vector_type(8))) short short8;
typedef __attribute__((ext_vector_type(4))) float f32x4;

__device__ inline u16 f2bf(float x) {
  unsigned int u = __float_as_uint(x);
  unsigned int r = (u + 0x7fffu + ((u >> 16) & 1u)) >> 16;
  return (u16)r;
}
__device__ inline float bf2f(u16 s) { return __uint_as_float(((unsigned int)s) << 16); }

// ---------------------------------------------------------------------------
// adjacency build: adj[b][s][t]=1 per edge; deg[row]+=1; ccount[col]+=1
__global__ void build_adj_kernel(const int* __restrict__ ei, float* __restrict__ adj,
                                 float* __restrict__ deg, int* __restrict__ ccount, int E) {
  int e = blockIdx.x * 256 + threadIdx.x;
  if (e >= E) return;
  int r = ei[e], c = ei[E + e];
  int b = r >> 8;
  adj[((size_t)b << 16) + ((size_t)(r & 255) << 8) + (c & 255)] = 1.0f;
  atomicAdd(&deg[r], 1.0f);
  atomicAdd(&ccount[c], 1);
}

// self loops on valid nodes; deg += 1; dis = deg^-1/2
__global__ void selfloop_deg_kernel(const int* __restrict__ nc, float* __restrict__ adj,
                                    float* __restrict__ deg, float* __restrict__ dis) {
  int n = blockIdx.x * 256 + threadIdx.x;
  int b = n >> 8, i = n & 255;
  if (i < nc[b]) adj[((size_t)b << 16) + ((size_t)i << 8) + i] = 1.0f;
  float d = deg[n] + 1.0f;
  deg[n] = d;
  dis[n] = rsqrtf(d);
}

// exclusive scan of ccount[4096] -> rowptr[4097]; one block of 1024 threads
__global__ __launch_bounds__(1024) void scan_kernel(const int* __restrict__ ccount,
                                                    int* __restrict__ rowptr, int n) {
  __shared__ int part[1024];
  int t = threadIdx.x;
  int base = t * 4;
  int c[4], s = 0;
#pragma unroll
  for (int i = 0; i < 4; i++) { c[i] = (base + i < n) ? ccount[base + i] : 0; s += c[i]; }
  part[t] = s;
  __syncthreads();
  for (int o = 1; o < 1024; o <<= 1) {
    int v = (t >= o) ? part[t - o] : 0;
    __syncthreads();
    part[t] += v;
    __syncthreads();
  }
  int excl = part[t] - s;
#pragma unroll
  for (int i = 0; i < 4; i++) {
    if (base + i < n) rowptr[base + i] = excl;
    excl += c[i];
  }
  if (t == 1023) rowptr[n] = part[1023];
}

// scatter edges into CSR order by target node; also precompute enorm
__global__ void scatter_kernel(const int* __restrict__ ei, const float* __restrict__ dis,
                               const int* __restrict__ rowptr, int* __restrict__ fill,
                               int* __restrict__ src_s, int* __restrict__ eidx_s,
                               float* __restrict__ enorm_s, int E) {
  int e = blockIdx.x * 256 + threadIdx.x;
  if (e >= E) return;
  int r = ei[e], c = ei[E + e];
  int pos = rowptr[c] + atomicAdd(&fill[c], 1);
  src_s[pos] = r;
  eidx_s[pos] = e;
  enorm_s[pos] = dis[r] * dis[c];
}

// row-normalize m = adj / rowsum: one block (256 thr) per row (fp32, once)
__global__ __launch_bounds__(256) void norm_rows_kernel(const float* __restrict__ src,
                                                        float* __restrict__ dst) {
  int row = blockIdx.x;
  int t = threadIdx.x;
  float v = src[(size_t)row * 256 + t];
  float s = v;
#pragma unroll
  for (int o = 32; o > 0; o >>= 1) s += __shfl_xor(s, o, 64);
  __shared__ float ws4[4];
  if ((t & 63) == 0) ws4[t >> 6] = s;
  __syncthreads();
  float tot = ws4[0] + ws4[1] + ws4[2] + ws4[3];
  dst[(size_t)row * 256 + t] = v / (tot + 1e-6f);
}

// m (fp32 row-major) -> mb (bf16 row-major) and rT0 (bf16 transposed); grid (4,4,B)
__global__ __launch_bounds__(256) void mcl_prep_kernel(const float* __restrict__ m,
                                                       u16* __restrict__ mb,
                                                       u16* __restrict__ rT) {
  int b = blockIdx.z;
  const float* M = m + ((size_t)b << 16);
  u16* MB = mb + ((size_t)b << 16);
  u16* RT = rT + ((size_t)b << 16);
  int r0 = blockIdx.x * 64, c0 = blockIdx.y * 64;
  __shared__ float ts[64][65];
  int t = threadIdx.x;
  int i = t >> 2, jb = (t & 3) * 16;
#pragma unroll
  for (int g = 0; g < 4; g++) {
    int j = jb + g * 4;
    float4 v = *(const float4*)(M + (size_t)(r0 + i) * 256 + c0 + j);
    ts[i][j] = v.x; ts[i][j + 1] = v.y; ts[i][j + 2] = v.z; ts[i][j + 3] = v.w;
    u16 p[4] = {f2bf(v.x), f2bf(v.y), f2bf(v.z), f2bf(v.w)};
    *(ushort4*)(MB + (size_t)(r0 + i) * 256 + c0 + j) = *(ushort4*)p;
  }
  __syncthreads();
#pragma unroll
  for (int g = 0; g < 4; g++) {
    int j = jb + g * 4;
    u16 p[4] = {f2bf(ts[j][i]), f2bf(ts[j + 1][i]), f2bf(ts[j + 2][i]), f2bf(ts[j + 3][i])};
    *(ushort4*)(RT + (size_t)(c0 + i) * 256 + r0 + j) = *(ushort4*)p;
  }
}

// cT = NT(rT, mb): cT[j][i] = sum_k rT[j][k]*mb[i][k]  (== (m@r)[i][j], transposed result)
// grid (4,4,B), 256 thr = 4 waves; wave w: rows [w*16,w*16+16) x 64 cols; bf16 MFMA
__global__ __launch_bounds__(256) void mcl_mfma_kernel(const u16* __restrict__ rT,
                                                       const u16* __restrict__ mb,
                                                       u16* __restrict__ cT) {
  int b = blockIdx.z;
  const u16* A = rT + ((size_t)b << 16);
  const u16* Bm = mb + ((size_t)b << 16);
  u16* C = cT + ((size_t)b << 16);
  int r0 = blockIdx.x * 64, c0 = blockIdx.y * 64;
  int w = threadIdx.x >> 6, lane = threadIdx.x & 63;
  int m16 = lane & 15, quad = lane >> 4;
  int arow = r0 + w * 16 + m16;
  f32x4 acc[4];
#pragma unroll
  for (int t = 0; t < 4; t++) acc[t] = (f32x4){0.f, 0.f, 0.f, 0.f};
  for (int k0 = 0; k0 < 256; k0 += 32) {
    short8 a = *(const short8*)(A + (size_t)arow * 256 + k0 + quad * 8);
#pragma unroll
    for (int t = 0; t < 4; t++) {
      short8 bf = *(const short8*)(Bm + (size_t)(c0 + t * 16 + m16) * 256 + k0 + quad * 8);
      acc[t] = __builtin_amdgcn_mfma_f32_16x16x32_bf16(a, bf, acc[t], 0, 0, 0);
    }
  }
  // C/D layout: col = lane&15, row = quad*4 + reg
#pragma unroll
  for (int t = 0; t < 4; t++)
#pragma unroll
    for (int reg = 0; reg < 4; reg++)
      C[(size_t)(r0 + w * 16 + quad * 4 + reg) * 256 + c0 + t * 16 + m16] = f2bf(acc[t][reg]);
}

// column-normalize cT (optionally v^6 inflation first): grid B*4, block 256.
// block handles 64 columns; 4 j-chunks of 64 per thread-group. fin: write fp32 mclT.
__global__ __launch_bounds__(256) void mcl_norm_kernel(const u16* __restrict__ cT,
                                                       u16* __restrict__ rT,
                                                       float* __restrict__ mclT, int inflate,
                                                       int fin) {
  int b = blockIdx.x >> 2, cg = blockIdx.x & 3;
  int col = cg * 64 + (threadIdx.x & 63);
  int jc = threadIdx.x >> 6;
  const u16* src = cT + ((size_t)b << 16);
  float s = 0.f;
#pragma unroll 8
  for (int j = jc * 64; j < jc * 64 + 64; j++) {
    float v = bf2f(src[(size_t)j * 256 + col]);
    if (inflate) { float v2 = v * v; v = v2 * v2 * v2; }
    s += v;
  }
  __shared__ float ps[4][64];
  __shared__ float invs[64];
  ps[jc][threadIdx.x & 63] = s;
  __syncthreads();
  if (threadIdx.x < 64) {
    float tot = ps[0][threadIdx.x] + ps[1][threadIdx.x] + ps[2][threadIdx.x] + ps[3][threadIdx.x];
    invs[threadIdx.x] = 1.f / (tot + 1e-6f);
  }
  __syncthreads();
  float inv = invs[threadIdx.x & 63];
  if (fin) {
    float* dst = mclT + ((size_t)b << 16);
#pragma unroll 8
    for (int j = jc * 64; j < jc * 64 + 64; j++) {
      float v = bf2f(src[(size_t)j * 256 + col]);
      if (inflate) { float v2 = v * v; v = v2 * v2 * v2; }
      dst[(size_t)j * 256 + col] = v * inv;
    }
  } else {
    u16* dst = rT + ((size_t)b << 16);
#pragma unroll 8
    for (int j = jc * 64; j < jc * 64 + 64; j++) {
      float v = bf2f(src[(size_t)j * 256 + col]);
      if (inflate) { float v2 = v * v; v = v2 * v2 * v2; }
      dst[(size_t)j * 256 + col] = f2bf(v * inv);
    }
  }
}

__device__ inline float gelu_exact(float x) {
  return 0.5f * x * (1.0f + erff(x * 0.7071067811865476f));
}

// C[M,O] = act(A[M,K] @ W[O,K]^T); ACT 0: *scale, 1: +bias, 2: gelu(x+bias)
template <int ACT>
__global__ __launch_bounds__(256) void gemm_nt_kernel(const float* __restrict__ A,
                                                      const float* __restrict__ W,
                                                      const float* __restrict__ bias,
                                                      float* __restrict__ C, int K, int O,
                                                      float scale) {
  int m0 = blockIdx.x * 64, o0 = blockIdx.y * 64;
  int t = threadIdx.x;
  __shared__ float As[16][64], Ws[16][64];
  int lr = t >> 2, lc = (t & 3) * 4;
  int tm = t >> 4, to = t & 15;
  float acc[4][4] = {};
  for (int kc = 0; kc < K; kc += 16) {
    float4 a4 = *(const float4*)(A + (size_t)(m0 + lr) * K + kc + lc);
    float4 w4 = *(const float4*)(W + (size_t)(o0 + lr) * K + kc + lc);
    As[lc + 0][lr] = a4.x; As[lc + 1][lr] = a4.y; As[lc + 2][lr] = a4.z; As[lc + 3][lr] = a4.w;
    Ws[lc + 0][lr] = w4.x; Ws[lc + 1][lr] = w4.y; Ws[lc + 2][lr] = w4.z; Ws[lc + 3][lr] = w4.w;
    __syncthreads();
#pragma unroll
    for (int kk = 0; kk < 16; kk++) {
      float av[4], bv[4];
#pragma unroll
      for (int i = 0; i < 4; i++) { av[i] = As[kk][tm * 4 + i]; bv[i] = Ws[kk][to * 4 + i]; }
#pragma unroll
      for (int i = 0; i < 4; i++)
#pragma unroll
        for (int j = 0; j < 4; j++) acc[i][j] += av[i] * bv[j];
    }
    __syncthreads();
  }
#pragma unroll
  for (int i = 0; i < 4; i++) {
    int m = m0 + tm * 4 + i;
#pragma unroll
    for (int j = 0; j < 4; j++) {
      int oo = o0 + to * 4 + j;
      float v = acc[i][j];
      if (ACT == 0) v *= scale;
      else if (ACT == 1) v += bias[oo];
      else if (ACT == 2) v = gelu_exact(v + bias[oo]);
      C[(size_t)m * O + oo] = v;
    }
  }
}

// fused QKV projection: grid (BN/64, 6); y>>1 selects {q,k,v}, y&1 selects col half
__global__ __launch_bounds__(256) void gemm_qkv_kernel(const float* __restrict__ A,
                                                       const float* __restrict__ qw,
                                                       const float* __restrict__ kw,
                                                       const float* __restrict__ vw,
                                                       float* __restrict__ qkv, int BN) {
  int y = blockIdx.y;
  int which = y >> 1;
  const float* W = (which == 0) ? qw : (which == 1) ? kw : vw;
  float scale = (which == 0) ? 0.25f : 1.0f;
  float* C = qkv + (size_t)which * BN * 128;
  int m0 = blockIdx.x * 64, o0 = (y & 1) * 64;
  int t = threadIdx.x;
  __shared__ float As[16][64], Ws[16][64];
  int lr = t >> 2, lc = (t & 3) * 4;
  int tm = t >> 4, to = t & 15;
  float acc[4][4] = {};
  for (int kc = 0; kc < 128; kc += 16) {
    float4 a4 = *(const float4*)(A + (size_t)(m0 + lr) * 128 + kc + lc);
    float4 w4 = *(const float4*)(W + (size_t)(o0 + lr) * 128 + kc + lc);
    As[lc + 0][lr] = a4.x; As[lc + 1][lr] = a4.y; As[lc + 2][lr] = a4.z; As[lc + 3][lr] = a4.w;
    Ws[lc + 0][lr] = w4.x; Ws[lc + 1][lr] = w4.y; Ws[lc + 2][lr] = w4.z; Ws[lc + 3][lr] = w4.w;
    __syncthreads();
#pragma unroll
    for (int kk = 0; kk < 16; kk++) {
      float av[4], bv[4];
#pragma unroll
      for (int i = 0; i < 4; i++) { av[i] = As[kk][tm * 4 + i]; bv[i] = Ws[kk][to * 4 + i]; }
#pragma unroll
      for (int i = 0; i < 4; i++)
#pragma unroll
        for (int j = 0; j < 4; j++) acc[i][j] += av[i] * bv[j];
    }
    __syncthreads();
  }
#pragma unroll
  for (int i = 0; i < 4; i++) {
    int m = m0 + tm * 4 + i;
#pragma unroll
    for (int j = 0; j < 4; j++) C[(size_t)m * 128 + o0 + to * 4 + j] = acc[i][j] * scale;
  }
}

// fused GCN aggregate + post: one wave per node (2 feats/lane), CSR edge loop, no atomics.
__global__ __launch_bounds__(256) void gcn_fused_kernel(
    const int* __restrict__ rowptr, const int* __restrict__ src_s,
    const int* __restrict__ eidx_s, const float* __restrict__ enorm_s,
    const float* __restrict__ ea, const float* __restrict__ We, const float* __restrict__ h,
    const float* __restrict__ remb, const int* __restrict__ root,
    const float* __restrict__ deg, const float* __restrict__ gamma,
    const float* __restrict__ beta, float* __restrict__ out) {
  __shared__ float Wt[7][128];  // transposed: Wt[k][f] = We[f*7+k]
  for (int idx = threadIdx.x; idx < 896; idx += 256) {
    int f = idx & 127, k = idx >> 7;
    Wt[k][f] = We[f * 7 + k];
  }
  __syncthreads();
  int n = blockIdx.x * 4 + (threadIdx.x >> 6);
  int lane = threadIdx.x & 63;
  int f0 = lane, f1 = lane + 64;
  int p0 = rowptr[n], p1 = rowptr[n + 1];
  float a0 = 0.f, a1 = 0.f;
  int r = 0, e = 0;
  float en = 0.f;
  if (p0 < p1) { r = src_s[p0]; e = eidx_s[p0]; en = enorm_s[p0]; }
  for (int p = p0; p < p1; p++) {
    int rn = 0, enx = 0;
    float ennx = 0.f;
    if (p + 1 < p1) { rn = src_s[p + 1]; enx = eidx_s[p + 1]; ennx = enorm_s[p + 1]; }
    const float* eae = ea + (size_t)e * 7;
    float h0 = h[(size_t)r * 128 + f0];
    float h1 = h[(size_t)r * 128 + f1];
    float d0 = 0.f, d1 = 0.f;
#pragma unroll
    for (int k = 0; k < 7; k++) {
      float ev = eae[k];
      d0 += ev * Wt[k][f0];
      d1 += ev * Wt[k][f1];
    }
    a0 += en * fmaxf(h0 + d0, 0.f);
    a1 += en * fmaxf(h1 + d1, 0.f);
    r = rn; e = enx; en = ennx;
  }
  float invd = 1.0f / deg[n];
  const float* re = remb + root[n] * 128;
  size_t base = (size_t)n * 128;
  float g0 = a0 + fmaxf(h[base + f0] + re[f0], 0.f) * invd;
  float g1 = a1 + fmaxf(h[base + f1] + re[f1], 0.f) * invd;
  float s = g0 + g1, ss = g0 * g0 + g1 * g1;
#pragma unroll
  for (int o = 32; o > 0; o >>= 1) { s += __shfl_xor(s, o, 64); ss += __shfl_xor(ss, o, 64); }
  float mu = s * 0.0078125f;
  float var = ss * 0.0078125f - mu * mu;
  float rs = rsqrtf(var + 1e-5f);
  float y0 = fmaxf((g0 - mu) * rs * gamma[f0] + beta[f0], 0.f);
  float y1 = fmaxf((g1 - mu) * rs * gamma[f1] + beta[f1], 0.f);
  out[base + f0] = y0 + out[base + f0];
  out[base + f1] = y1 + out[base + f1];
}

// dst = LN(a (+ res)) * gamma + beta
__global__ __launch_bounds__(256) void ln_add_kernel(const float* __restrict__ a,
                                                     const float* __restrict__ res,
                                                     const float* __restrict__ gamma,
                                                     const float* __restrict__ beta,
                                                     float* __restrict__ dst) {
  int n = blockIdx.x * 4 + (threadIdx.x >> 6);
  int lane = threadIdx.x & 63;
  size_t base = (size_t)n * 128;
  int f0 = lane, f1 = lane + 64;
  float x0 = a[base + f0], x1 = a[base + f1];
  if (res) { x0 += res[base + f0]; x1 += res[base + f1]; }
  float s = x0 + x1, ss = x0 * x0 + x1 * x1;
#pragma unroll
  for (int o = 32; o > 0; o >>= 1) { s += __shfl_xor(s, o, 64); ss += __shfl_xor(ss, o, 64); }
  float mu = s * 0.0078125f;
  float var = ss * 0.0078125f - mu * mu;
  float rs = rsqrtf(var + 1e-5f);
  dst[base + f0] = (x0 - mu) * rs * gamma[f0] + beta[f0];
  dst[base + f1] = (x1 - mu) * rs * gamma[f1] + beta[f1];
}

// biased MHA v3: 4 lanes per query (d split 4x4), fixed-max softmax, transposed mcl.
// grid (4, H, B), block 256 (4 waves = 64 queries)
__global__ __launch_bounds__(256) void attn4_kernel(const float* __restrict__ q,
                                                    const float* __restrict__ k,
                                                    const float* __restrict__ v,
                                                    const float* __restrict__ mclT,
                                                    const float* __restrict__ mclw,
                                                    const int* __restrict__ ncnt,
                                                    float* __restrict__ o) {
  int qt = blockIdx.x, hh = blockIdx.y, b = blockIdx.z;
  int t = threadIdx.x;
  __shared__ float ks[256][16];
  __shared__ float vs[256][16];
  {
    const float* kp = k + ((size_t)(b * 256 + t) * 128 + hh * 16);
    const float* vp = v + ((size_t)(b * 256 + t) * 128 + hh * 16);
#pragma unroll
    for (int d4 = 0; d4 < 16; d4 += 4) {
      *(float4*)&ks[t][d4] = *(const float4*)(kp + d4);
      *(float4*)&vs[t][d4] = *(const float4*)(vp + d4);
    }
  }
  __syncthreads();
  int i = qt * 64 + (t >> 2);
  int d0 = (t & 3) * 4;
  int nc = ncnt[b];
  bool vi = i < nc;
  float wh = mclw[hh];
  const float* qp = q + ((size_t)(b * 256 + i) * 128 + hh * 16 + d0);
  float qv[4] = {qp[0], qp[1], qp[2], qp[3]};
  const float* mp = mclT + ((size_t)b << 16) + i;  // mclT[b][j][i], stride 256 over j
  float acc[4] = {0.f, 0.f, 0.f, 0.f};
  float lsum = 0.f;
  for (int j0 = 0; j0 < 256; j0 += 4) {
#pragma unroll
    for (int jj = 0; jj < 4; jj++) {
      int j = j0 + jj;
      float s = qv[0] * ks[j][d0] + qv[1] * ks[j][d0 + 1] + qv[2] * ks[j][d0 + 2] +
                qv[3] * ks[j][d0 + 3];
      s += __shfl_xor(s, 1, 64);
      s += __shfl_xor(s, 2, 64);
      float bias = mp[(size_t)j * 256] * wh + ((vi && j >= nc) ? -1024.f : 0.f);
      float p = __expf(s + bias);
      lsum += p;
      acc[0] += p * vs[j][d0];
      acc[1] += p * vs[j][d0 + 1];
      acc[2] += p * vs[j][d0 + 2];
      acc[3] += p * vs[j][d0 + 3];
    }
  }
  float inv = 1.f / lsum;
  float4 o4 = {acc[0] * inv, acc[1] * inv, acc[2] * inv, acc[3] * inv};
  *(float4*)(o + ((size_t)(b * 256 + i) * 128 + hh * 16 + d0)) = o4;
}

// ---------------------------------------------------------------------------
extern "C" void kernel_launch(void* const* d_in, const int* in_sizes, int n_in,
                              void* d_out, int out_size, void* d_ws, size_t ws_size,
                              hipStream_t stream) {
  const float* input_x = (const float*)d_in[0];
  const float* edge_attr = (const float*)d_in[1];
  const float* gcn_lin_w = (const float*)d_in[2];
  const float* gcn_root = (const float*)d_in[3];
  const float* gcn_edge_w = (const float*)d_in[4];
  const float* gcn_ng = (const float*)d_in[5];
  const float* gcn_nb = (const float*)d_in[6];
  const float* ln_in_g = (const float*)d_in[7];
  const float* ln_in_b = (const float*)d_in[8];
  const float* ln_ffn_g = (const float*)d_in[9];
  const float* ln_ffn_b = (const float*)d_in[10];
  const float* mcl_w = (const float*)d_in[11];
  const float* q_w = (const float*)d_in[12];
  const float* k_w = (const float*)d_in[13];
  const float* v_w = (const float*)d_in[14];
  const float* merge_w = (const float*)d_in[15];
  const float* merge_b = (const float*)d_in[16];
  const float* ffn_w1 = (const float*)d_in[17];
  const float* ffn_b1 = (const float*)d_in[18];
  const float* ffn_w2 = (const float*)d_in[19];
  const float* ffn_b2 = (const float*)d_in[20];
  const float* final_g = (const float*)d_in[21];
  const float* final_b = (const float*)d_in[22];
  const int* edge_index = (const int*)d_in[23];
  const int* n_counts = (const int*)d_in[24];
  const int* root = (const int*)d_in[25];

  const int E = in_sizes[23] / 2;
  const int B = in_sizes[24];
  const int BN = B * NNODE;

  float* ws = (float*)d_ws;
  size_t off = 0;
  auto alloc = [&](size_t n) { float* p = ws + off; off += n; return p; };
  const size_t NN2 = (size_t)B * 256 * 256;
  const size_t XF = (size_t)BN * 128;
  float* mclr = alloc(NN2);   // mclT fp32 (persists across layers)
  float* mbuf = alloc(NN2);   // adj/m; later qkv (spans into rt)
  float* rt = alloc(NN2);     // layer temps: qkv tail + ob, then f1
  float* hbuf = alloc(XF);    // h; later f2
  float* xbuf = alloc(XF);    // post-attn LN output (FFN residual)
  float* deg = alloc(BN);
  float* dis = alloc(BN);
  int* rowptr = (int*)alloc(BN + 1);
  int* ccount = (int*)alloc(BN);
  int* fill = (int*)alloc(BN);
  int* src_s = (int*)alloc(E);
  int* eidx_s = (int*)alloc(E);
  float* enorm_s = alloc(E);
  u16* mb16 = (u16*)alloc(NN2 / 2);  // m in bf16
  u16* rT16 = (u16*)alloc(NN2 / 2);  // r transposed, bf16
  u16* cT16 = (u16*)alloc(NN2 / 2);  // matmul temp

  // layer-temp aliasing (mbuf+rt = 2*NN2 contiguous floats)
  float* qkv = mbuf;          // 3*XF <= 2*NN2
  float* ob = mbuf + 3 * XF;  // attn output
  float* om = mbuf;           // merge output (q/k/v dead)
  float* f1 = rt;             // FFN hidden; BN*256 = NN2
  float* f2 = hbuf;           // h dead after gcn_fused
  float* outb = (float*)d_out;

  // ---- one-time: adjacency, degree, CSR, MCL ----
  hipMemsetAsync(mbuf, 0, NN2 * sizeof(float), stream);
  hipMemsetAsync(deg, 0, BN * sizeof(float), stream);
  hipMemsetAsync(ccount, 0, BN * sizeof(int), stream);
  hipMemsetAsync(fill, 0, BN * sizeof(int), stream);
  build_adj_kernel<<<(E + 255) / 256, 256, 0, stream>>>(edge_index, mbuf, deg, ccount, E);
  selfloop_deg_kernel<<<BN / 256, 256, 0, stream>>>(n_counts, mbuf, deg, dis);
  scan_kernel<<<1, 1024, 0, stream>>>(ccount, rowptr, BN);
  scatter_kernel<<<(E + 255) / 256, 256, 0, stream>>>(edge_index, dis, rowptr, fill, src_s,
                                                      eidx_s, enorm_s, E);
  norm_rows_kernel<<<BN, 256, 0, stream>>>(mbuf, mbuf);
  dim3 mmg(4, 4, B);
  mcl_prep_kernel<<<mmg, 256, 0, stream>>>(mbuf, mb16, rT16);
  for (int it = 0; it < 6; it++) {
    mcl_mfma_kernel<<<mmg, 256, 0, stream>>>(rT16, mb16, cT16);
    int inflate = (it == 2 || it == 5) ? 1 : 0;
    mcl_norm_kernel<<<B * 4, 256, 0, stream>>>(cT16, rT16, mclr, inflate, it == 5 ? 1 : 0);
  }

  // ---- running activation lives in d_out ----
  hipMemcpyAsync(outb, input_x, XF * sizeof(float), hipMemcpyDeviceToDevice, stream);

  dim3 g64x2(BN / 64, 2), g64x4(BN / 64, 4), g64x6(BN / 64, 6);
  dim3 ag(4, NHEAD, B);
  for (int l = 0; l < NLAYER; l++) {
    // GCN
    gemm_nt_kernel<0><<<g64x2, 256, 0, stream>>>(outb, gcn_lin_w + (size_t)l * 128 * 128,
                                                 nullptr, hbuf, 128, 128, 1.0f);
    gcn_fused_kernel<<<BN / 4, 256, 0, stream>>>(
        rowptr, src_s, eidx_s, enorm_s, edge_attr, gcn_edge_w + (size_t)l * 128 * 7, hbuf,
        gcn_root + (size_t)l * 2 * 128, root, deg, gcn_ng + l * 128, gcn_nb + l * 128, outb);
    // attention
    gemm_qkv_kernel<<<g64x6, 256, 0, stream>>>(outb, q_w + (size_t)l * 128 * 128,
                                               k_w + (size_t)l * 128 * 128,
                                               v_w + (size_t)l * 128 * 128, qkv, BN);
    attn4_kernel<<<ag, 256, 0, stream>>>(qkv, qkv + XF, qkv + 2 * XF, mclr,
                                         mcl_w + l * NHEAD, n_counts, ob);
    gemm_nt_kernel<1><<<g64x2, 256, 0, stream>>>(ob, merge_w + (size_t)l * 128 * 128,
                                                 merge_b + l * 128, om, 128, 128, 1.0f);
    ln_add_kernel<<<BN / 4, 256, 0, stream>>>(om, outb, ln_in_g + l * 128, ln_in_b + l * 128,
                                              xbuf);
    // FFN
    gemm_nt_kernel<2><<<g64x4, 256, 0, stream>>>(xbuf, ffn_w1 + (size_t)l * 256 * 128,
                                                 ffn_b1 + l * 256, f1, 128, 256, 1.0f);
    gemm_nt_kernel<1><<<g64x2, 256, 0, stream>>>(f1, ffn_w2 + (size_t)l * 128 * 256,
                                                 ffn_b2 + l * 128, f2, 256, 128, 1.0f);
    ln_add_kernel<<<BN / 4, 256, 0, stream>>>(f2, xbuf, ln_ffn_g + l * 128,
                                              ln_ffn_b + l * 128, outb);
  }
  // final layernorm (in place on d_out)
  ln_add_kernel<<<BN / 4, 256, 0, stream>>>(outb, nullptr, final_g, final_b, outb);
}

// Round 4
// 998.863 us; speedup vs baseline: 1.2686x; 1.2686x over previous
//
#include <hip/hip_runtime.h>
#include <hip/hip_bf16.h>
#include <math.h>

#define NFEAT 128
#define NNODE 256
#define NHEAD 8
#define DHEAD 16
#define NLAYER 9

typedef unsigned short u16;
typedef __attribute__((ext_vector_type(8))) short short8;
typedef __attribute__((ext_vector_type(4))) float f32x4;

__device__ inline u16 f2bf(float x) {
  unsigned int u = __float_as_uint(x);
  unsigned int r = (u + 0x7fffu + ((u >> 16) & 1u)) >> 16;
  return (u16)r;
}
__device__ inline float bf2f(u16 s) { return __uint_as_float(((unsigned int)s) << 16); }

// ---------------------------------------------------------------------------
__global__ void build_adj_kernel(const int* __restrict__ ei, float* __restrict__ adj,
                                 float* __restrict__ deg, int* __restrict__ ccount, int E) {
  int e = blockIdx.x * 256 + threadIdx.x;
  if (e >= E) return;
  int r = ei[e], c = ei[E + e];
  int b = r >> 8;
  adj[((size_t)b << 16) + ((size_t)(r & 255) << 8) + (c & 255)] = 1.0f;
  atomicAdd(&deg[r], 1.0f);
  atomicAdd(&ccount[c], 1);
}

__global__ void selfloop_deg_kernel(const int* __restrict__ nc, float* __restrict__ adj,
                                    float* __restrict__ deg, float* __restrict__ dis) {
  int n = blockIdx.x * 256 + threadIdx.x;
  int b = n >> 8, i = n & 255;
  if (i < nc[b]) adj[((size_t)b << 16) + ((size_t)i << 8) + i] = 1.0f;
  float d = deg[n] + 1.0f;
  deg[n] = d;
  dis[n] = rsqrtf(d);
}

__global__ __launch_bounds__(1024) void scan_kernel(const int* __restrict__ ccount,
                                                    int* __restrict__ rowptr, int n) {
  __shared__ int part[1024];
  int t = threadIdx.x;
  int base = t * 4;
  int c[4], s = 0;
#pragma unroll
  for (int i = 0; i < 4; i++) { c[i] = (base + i < n) ? ccount[base + i] : 0; s += c[i]; }
  part[t] = s;
  __syncthreads();
  for (int o = 1; o < 1024; o <<= 1) {
    int v = (t >= o) ? part[t - o] : 0;
    __syncthreads();
    part[t] += v;
    __syncthreads();
  }
  int excl = part[t] - s;
#pragma unroll
  for (int i = 0; i < 4; i++) {
    if (base + i < n) rowptr[base + i] = excl;
    excl += c[i];
  }
  if (t == 1023) rowptr[n] = part[1023];
}

__global__ void scatter_kernel(const int* __restrict__ ei, const float* __restrict__ dis,
                               const int* __restrict__ rowptr, int* __restrict__ fill,
                               int* __restrict__ src_s, int* __restrict__ eidx_s,
                               float* __restrict__ enorm_s, int E) {
  int e = blockIdx.x * 256 + threadIdx.x;
  if (e >= E) return;
  int r = ei[e], c = ei[E + e];
  int pos = rowptr[c] + atomicAdd(&fill[c], 1);
  src_s[pos] = r;
  eidx_s[pos] = e;
  enorm_s[pos] = dis[r] * dis[c];
}

__global__ __launch_bounds__(256) void norm_rows_kernel(const float* __restrict__ src,
                                                        float* __restrict__ dst) {
  int row = blockIdx.x;
  int t = threadIdx.x;
  float v = src[(size_t)row * 256 + t];
  float s = v;
#pragma unroll
  for (int o = 32; o > 0; o >>= 1) s += __shfl_xor(s, o, 64);
  __shared__ float ws4[4];
  if ((t & 63) == 0) ws4[t >> 6] = s;
  __syncthreads();
  float tot = ws4[0] + ws4[1] + ws4[2] + ws4[3];
  dst[(size_t)row * 256 + t] = v / (tot + 1e-6f);
}

// m (fp32 row-major) -> mb (bf16 row-major) and rT0 (bf16 transposed); grid (4,4,B)
__global__ __launch_bounds__(256) void mcl_prep_kernel(const float* __restrict__ m,
                                                       u16* __restrict__ mb,
                                                       u16* __restrict__ rT) {
  int b = blockIdx.z;
  const float* M = m + ((size_t)b << 16);
  u16* MB = mb + ((size_t)b << 16);
  u16* RT = rT + ((size_t)b << 16);
  int r0 = blockIdx.x * 64, c0 = blockIdx.y * 64;
  __shared__ float ts[64][65];
  int t = threadIdx.x;
  int i = t >> 2, jb = (t & 3) * 16;
#pragma unroll
  for (int g = 0; g < 4; g++) {
    int j = jb + g * 4;
    float4 v = *(const float4*)(M + (size_t)(r0 + i) * 256 + c0 + j);
    ts[i][j] = v.x; ts[i][j + 1] = v.y; ts[i][j + 2] = v.z; ts[i][j + 3] = v.w;
    u16 p[4] = {f2bf(v.x), f2bf(v.y), f2bf(v.z), f2bf(v.w)};
    *(ushort4*)(MB + (size_t)(r0 + i) * 256 + c0 + j) = *(ushort4*)p;
  }
  __syncthreads();
#pragma unroll
  for (int g = 0; g < 4; g++) {
    int j = jb + g * 4;
    u16 p[4] = {f2bf(ts[j][i]), f2bf(ts[j + 1][i]), f2bf(ts[j + 2][i]), f2bf(ts[j + 3][i])};
    *(ushort4*)(RT + (size_t)(c0 + i) * 256 + r0 + j) = *(ushort4*)p;
  }
}

// cT = NT(rT, mb); grid (4,4,B), 4 waves: wave w rows [w*16..w*16+16) x 64 cols
__global__ __launch_bounds__(256) void mcl_mfma_kernel(const u16* __restrict__ rT,
                                                       const u16* __restrict__ mb,
                                                       u16* __restrict__ cT) {
  int b = blockIdx.z;
  const u16* A = rT + ((size_t)b << 16);
  const u16* Bm = mb + ((size_t)b << 16);
  u16* C = cT + ((size_t)b << 16);
  int r0 = blockIdx.x * 64, c0 = blockIdx.y * 64;
  int w = threadIdx.x >> 6, lane = threadIdx.x & 63;
  int m16 = lane & 15, quad = lane >> 4;
  int arow = r0 + w * 16 + m16;
  f32x4 acc[4];
#pragma unroll
  for (int t = 0; t < 4; t++) acc[t] = (f32x4){0.f, 0.f, 0.f, 0.f};
  for (int k0 = 0; k0 < 256; k0 += 32) {
    short8 a = *(const short8*)(A + (size_t)arow * 256 + k0 + quad * 8);
#pragma unroll
    for (int t = 0; t < 4; t++) {
      short8 bf = *(const short8*)(Bm + (size_t)(c0 + t * 16 + m16) * 256 + k0 + quad * 8);
      acc[t] = __builtin_amdgcn_mfma_f32_16x16x32_bf16(a, bf, acc[t], 0, 0, 0);
    }
  }
#pragma unroll
  for (int t = 0; t < 4; t++)
#pragma unroll
    for (int reg = 0; reg < 4; reg++)
      C[(size_t)(r0 + w * 16 + quad * 4 + reg) * 256 + c0 + t * 16 + m16] = f2bf(acc[t][reg]);
}

// column-normalize cT (optional inflation); fin: write fp32 mclT
__global__ __launch_bounds__(256) void mcl_norm_kernel(const u16* __restrict__ cT,
                                                       u16* __restrict__ rT,
                                                       float* __restrict__ mclT, int inflate,
                                                       int fin) {
  int b = blockIdx.x >> 2, cg = blockIdx.x & 3;
  int col = cg * 64 + (threadIdx.x & 63);
  int jc = threadIdx.x >> 6;
  const u16* src = cT + ((size_t)b << 16);
  float s = 0.f;
#pragma unroll 8
  for (int j = jc * 64; j < jc * 64 + 64; j++) {
    float v = bf2f(src[(size_t)j * 256 + col]);
    if (inflate) { float v2 = v * v; v = v2 * v2 * v2; }
    s += v;
  }
  __shared__ float ps[4][64];
  __shared__ float invs[64];
  ps[jc][threadIdx.x & 63] = s;
  __syncthreads();
  if (threadIdx.x < 64) {
    float tot = ps[0][threadIdx.x] + ps[1][threadIdx.x] + ps[2][threadIdx.x] + ps[3][threadIdx.x];
    invs[threadIdx.x] = 1.f / (tot + 1e-6f);
  }
  __syncthreads();
  float inv = invs[threadIdx.x & 63];
  if (fin) {
    float* dst = mclT + ((size_t)b << 16);
#pragma unroll 8
    for (int j = jc * 64; j < jc * 64 + 64; j++) {
      float v = bf2f(src[(size_t)j * 256 + col]);
      if (inflate) { float v2 = v * v; v = v2 * v2 * v2; }
      dst[(size_t)j * 256 + col] = v * inv;
    }
  } else {
    u16* dst = rT + ((size_t)b << 16);
#pragma unroll 8
    for (int j = jc * 64; j < jc * 64 + 64; j++) {
      float v = bf2f(src[(size_t)j * 256 + col]);
      if (inflate) { float v2 = v * v; v = v2 * v2 * v2; }
      dst[(size_t)j * 256 + col] = f2bf(v * inv);
    }
  }
}

__device__ inline float gelu_exact(float x) {
  return 0.5f * x * (1.0f + erff(x * 0.7071067811865476f));
}

// copy input_x to fp32 out + bf16 mirror
__global__ void copy_x_kernel(const float* __restrict__ x, float* __restrict__ out,
                              u16* __restrict__ out16) {
  int idx = blockIdx.x * 256 + threadIdx.x;
  float v = x[idx];
  out[idx] = v;
  out16[idx] = f2bf(v);
}

// convert 7 weight families fp32->bf16; grid.y = family
__global__ void conv_w_kernel(const float* __restrict__ s0, const float* __restrict__ s1,
                              const float* __restrict__ s2, const float* __restrict__ s3,
                              const float* __restrict__ s4, const float* __restrict__ s5,
                              const float* __restrict__ s6, u16* __restrict__ d0,
                              u16* __restrict__ d1, u16* __restrict__ d2,
                              u16* __restrict__ d3, u16* __restrict__ d4,
                              u16* __restrict__ d5, u16* __restrict__ d6) {
  int f = blockIdx.y;
  const float* s;
  u16* d;
  int n;
  switch (f) {
    case 0: s = s0; d = d0; n = NLAYER * 128 * 128; break;
    case 1: s = s1; d = d1; n = NLAYER * 128 * 128; break;
    case 2: s = s2; d = d2; n = NLAYER * 128 * 128; break;
    case 3: s = s3; d = d3; n = NLAYER * 128 * 128; break;
    case 4: s = s4; d = d4; n = NLAYER * 128 * 128; break;
    case 5: s = s5; d = d5; n = NLAYER * 256 * 128; break;
    default: s = s6; d = d6; n = NLAYER * 128 * 256; break;
  }
  int stride = gridDim.x * 256;
  for (int i = blockIdx.x * 256 + threadIdx.x; i < n / 4; i += stride) {
    float4 v = ((const float4*)s)[i];
    u16 p[4] = {f2bf(v.x), f2bf(v.y), f2bf(v.z), f2bf(v.w)};
    ((ushort4*)d)[i] = *(ushort4*)p;
  }
}

// bf16 MFMA NT GEMM: C[M,O] = epi(A[M,K] @ W[O,K]^T)
// grid (M/64, O/32), 4 waves; wave w: rows m0+w*16.. , 32 cols.
// ACT 0: *scale  1: +bias  2: gelu(x+bias). OBF: write bf16 C16 instead of fp32 C.
template <int K, int ACT, int OBF>
__global__ __launch_bounds__(256) void mfma_nt_kernel(const u16* __restrict__ A,
                                                      const u16* __restrict__ W,
                                                      const float* __restrict__ bias,
                                                      float* __restrict__ C,
                                                      u16* __restrict__ C16, int O,
                                                      float scale) {
  int m0 = blockIdx.x * 64, o0 = blockIdx.y * 32;
  int w = threadIdx.x >> 6, lane = threadIdx.x & 63;
  int m16 = lane & 15, quad = lane >> 4;
  const u16* arow = A + (size_t)(m0 + w * 16 + m16) * K + quad * 8;
  const u16* brow0 = W + (size_t)(o0 + m16) * K + quad * 8;
  const u16* brow1 = W + (size_t)(o0 + 16 + m16) * K + quad * 8;
  f32x4 acc0 = {0.f, 0.f, 0.f, 0.f}, acc1 = {0.f, 0.f, 0.f, 0.f};
#pragma unroll
  for (int k0 = 0; k0 < K; k0 += 32) {
    short8 a = *(const short8*)(arow + k0);
    short8 b0 = *(const short8*)(brow0 + k0);
    short8 b1 = *(const short8*)(brow1 + k0);
    acc0 = __builtin_amdgcn_mfma_f32_16x16x32_bf16(a, b0, acc0, 0, 0, 0);
    acc1 = __builtin_amdgcn_mfma_f32_16x16x32_bf16(a, b1, acc1, 0, 0, 0);
  }
  int col0 = o0 + m16, col1 = o0 + 16 + m16;
  float bi0 = (ACT >= 1) ? bias[col0] : 0.f;
  float bi1 = (ACT >= 1) ? bias[col1] : 0.f;
#pragma unroll
  for (int reg = 0; reg < 4; reg++) {
    int row = m0 + w * 16 + quad * 4 + reg;
    float v0 = acc0[reg], v1 = acc1[reg];
    if (ACT == 0) { v0 *= scale; v1 *= scale; }
    else if (ACT == 1) { v0 += bi0; v1 += bi1; }
    else { v0 = gelu_exact(v0 + bi0); v1 = gelu_exact(v1 + bi1); }
    if (OBF) {
      C16[(size_t)row * O + col0] = f2bf(v0);
      C16[(size_t)row * O + col1] = f2bf(v1);
    } else {
      C[(size_t)row * O + col0] = v0;
      C[(size_t)row * O + col1] = v1;
    }
  }
}

// fused QKV: grid (M/64, 12); y>>2 selects {q,k,v}, y&3 selects 32-col tile
__global__ __launch_bounds__(256) void mfma_qkv_kernel(const u16* __restrict__ A,
                                                       const u16* __restrict__ qw,
                                                       const u16* __restrict__ kw,
                                                       const u16* __restrict__ vw,
                                                       float* __restrict__ qkv, int BN) {
  int y = blockIdx.y;
  int which = y >> 2;
  const u16* W = (which == 0) ? qw : (which == 1) ? kw : vw;
  float scale = (which == 0) ? 0.25f : 1.0f;
  float* C = qkv + (size_t)which * BN * 128;
  int m0 = blockIdx.x * 64, o0 = (y & 3) * 32;
  int w = threadIdx.x >> 6, lane = threadIdx.x & 63;
  int m16 = lane & 15, quad = lane >> 4;
  const u16* arow = A + (size_t)(m0 + w * 16 + m16) * 128 + quad * 8;
  const u16* brow0 = W + (size_t)(o0 + m16) * 128 + quad * 8;
  const u16* brow1 = W + (size_t)(o0 + 16 + m16) * 128 + quad * 8;
  f32x4 acc0 = {0.f, 0.f, 0.f, 0.f}, acc1 = {0.f, 0.f, 0.f, 0.f};
#pragma unroll
  for (int k0 = 0; k0 < 128; k0 += 32) {
    short8 a = *(const short8*)(arow + k0);
    short8 b0 = *(const short8*)(brow0 + k0);
    short8 b1 = *(const short8*)(brow1 + k0);
    acc0 = __builtin_amdgcn_mfma_f32_16x16x32_bf16(a, b0, acc0, 0, 0, 0);
    acc1 = __builtin_amdgcn_mfma_f32_16x16x32_bf16(a, b1, acc1, 0, 0, 0);
  }
#pragma unroll
  for (int reg = 0; reg < 4; reg++) {
    int row = m0 + w * 16 + quad * 4 + reg;
    C[(size_t)row * 128 + o0 + m16] = acc0[reg] * scale;
    C[(size_t)row * 128 + o0 + 16 + m16] = acc1[reg] * scale;
  }
}

// fused GCN aggregate + post (CSR, no atomics); writes fp32 out + bf16 mirror
__global__ __launch_bounds__(256) void gcn_fused_kernel(
    const int* __restrict__ rowptr, const int* __restrict__ src_s,
    const int* __restrict__ eidx_s, const float* __restrict__ enorm_s,
    const float* __restrict__ ea, const float* __restrict__ We, const float* __restrict__ h,
    const float* __restrict__ remb, const int* __restrict__ root,
    const float* __restrict__ deg, const float* __restrict__ gamma,
    const float* __restrict__ beta, float* __restrict__ out, u16* __restrict__ out16) {
  __shared__ float Wt[7][128];
  for (int idx = threadIdx.x; idx < 896; idx += 256) {
    int f = idx & 127, k = idx >> 7;
    Wt[k][f] = We[f * 7 + k];
  }
  __syncthreads();
  int n = blockIdx.x * 4 + (threadIdx.x >> 6);
  int lane = threadIdx.x & 63;
  int f0 = lane, f1 = lane + 64;
  int p0 = rowptr[n], p1 = rowptr[n + 1];
  float a0 = 0.f, a1 = 0.f;
  int r = 0, e = 0;
  float en = 0.f;
  if (p0 < p1) { r = src_s[p0]; e = eidx_s[p0]; en = enorm_s[p0]; }
  for (int p = p0; p < p1; p++) {
    int rn = 0, enx = 0;
    float ennx = 0.f;
    if (p + 1 < p1) { rn = src_s[p + 1]; enx = eidx_s[p + 1]; ennx = enorm_s[p + 1]; }
    const float* eae = ea + (size_t)e * 7;
    float h0 = h[(size_t)r * 128 + f0];
    float h1 = h[(size_t)r * 128 + f1];
    float d0 = 0.f, d1 = 0.f;
#pragma unroll
    for (int k = 0; k < 7; k++) {
      float ev = eae[k];
      d0 += ev * Wt[k][f0];
      d1 += ev * Wt[k][f1];
    }
    a0 += en * fmaxf(h0 + d0, 0.f);
    a1 += en * fmaxf(h1 + d1, 0.f);
    r = rn; e = enx; en = ennx;
  }
  float invd = 1.0f / deg[n];
  const float* re = remb + root[n] * 128;
  size_t base = (size_t)n * 128;
  float g0 = a0 + fmaxf(h[base + f0] + re[f0], 0.f) * invd;
  float g1 = a1 + fmaxf(h[base + f1] + re[f1], 0.f) * invd;
  float s = g0 + g1, ss = g0 * g0 + g1 * g1;
#pragma unroll
  for (int o = 32; o > 0; o >>= 1) { s += __shfl_xor(s, o, 64); ss += __shfl_xor(ss, o, 64); }
  float mu = s * 0.0078125f;
  float var = ss * 0.0078125f - mu * mu;
  float rs = rsqrtf(var + 1e-5f);
  float y0 = fmaxf((g0 - mu) * rs * gamma[f0] + beta[f0], 0.f) + out[base + f0];
  float y1 = fmaxf((g1 - mu) * rs * gamma[f1] + beta[f1], 0.f) + out[base + f1];
  out[base + f0] = y0;
  out[base + f1] = y1;
  out16[base + f0] = f2bf(y0);
  out16[base + f1] = f2bf(y1);
}

// dst = LN(a (+ res)); optional bf16 mirror
__global__ __launch_bounds__(256) void ln_add_kernel(const float* __restrict__ a,
                                                     const float* __restrict__ res,
                                                     const float* __restrict__ gamma,
                                                     const float* __restrict__ beta,
                                                     float* __restrict__ dst,
                                                     u16* __restrict__ dst16) {
  int n = blockIdx.x * 4 + (threadIdx.x >> 6);
  int lane = threadIdx.x & 63;
  size_t base = (size_t)n * 128;
  int f0 = lane, f1 = lane + 64;
  float x0 = a[base + f0], x1 = a[base + f1];
  if (res) { x0 += res[base + f0]; x1 += res[base + f1]; }
  float s = x0 + x1, ss = x0 * x0 + x1 * x1;
#pragma unroll
  for (int o = 32; o > 0; o >>= 1) { s += __shfl_xor(s, o, 64); ss += __shfl_xor(ss, o, 64); }
  float mu = s * 0.0078125f;
  float var = ss * 0.0078125f - mu * mu;
  float rs = rsqrtf(var + 1e-5f);
  float y0 = (x0 - mu) * rs * gamma[f0] + beta[f0];
  float y1 = (x1 - mu) * rs * gamma[f1] + beta[f1];
  dst[base + f0] = y0;
  dst[base + f1] = y1;
  if (dst16) {
    dst16[base + f0] = f2bf(y0);
    dst16[base + f1] = f2bf(y1);
  }
}

// biased MHA: 4 lanes per query, fixed-max softmax, transposed mcl; bf16 output
__global__ __launch_bounds__(256) void attn4_kernel(const float* __restrict__ q,
                                                    const float* __restrict__ k,
                                                    const float* __restrict__ v,
                                                    const float* __restrict__ mclT,
                                                    const float* __restrict__ mclw,
                                                    const int* __restrict__ ncnt,
                                                    u16* __restrict__ o) {
  int qt = blockIdx.x, hh = blockIdx.y, b = blockIdx.z;
  int t = threadIdx.x;
  __shared__ float ks[256][16];
  __shared__ float vs[256][16];
  {
    const float* kp = k + ((size_t)(b * 256 + t) * 128 + hh * 16);
    const float* vp = v + ((size_t)(b * 256 + t) * 128 + hh * 16);
#pragma unroll
    for (int d4 = 0; d4 < 16; d4 += 4) {
      *(float4*)&ks[t][d4] = *(const float4*)(kp + d4);
      *(float4*)&vs[t][d4] = *(const float4*)(vp + d4);
    }
  }
  __syncthreads();
  int i = qt * 64 + (t >> 2);
  int d0 = (t & 3) * 4;
  int nc = ncnt[b];
  bool vi = i < nc;
  float wh = mclw[hh];
  const float* qp = q + ((size_t)(b * 256 + i) * 128 + hh * 16 + d0);
  float qv[4] = {qp[0], qp[1], qp[2], qp[3]};
  const float* mp = mclT + ((size_t)b << 16) + i;
  float acc[4] = {0.f, 0.f, 0.f, 0.f};
  float lsum = 0.f;
  for (int j0 = 0; j0 < 256; j0 += 4) {
#pragma unroll
    for (int jj = 0; jj < 4; jj++) {
      int j = j0 + jj;
      float s = qv[0] * ks[j][d0] + qv[1] * ks[j][d0 + 1] + qv[2] * ks[j][d0 + 2] +
                qv[3] * ks[j][d0 + 3];
      s += __shfl_xor(s, 1, 64);
      s += __shfl_xor(s, 2, 64);
      float bias = mp[(size_t)j * 256] * wh + ((vi && j >= nc) ? -1024.f : 0.f);
      float p = __expf(s + bias);
      lsum += p;
      acc[0] += p * vs[j][d0];
      acc[1] += p * vs[j][d0 + 1];
      acc[2] += p * vs[j][d0 + 2];
      acc[3] += p * vs[j][d0 + 3];
    }
  }
  float inv = 1.f / lsum;
  u16 p4[4] = {f2bf(acc[0] * inv), f2bf(acc[1] * inv), f2bf(acc[2] * inv), f2bf(acc[3] * inv)};
  *(ushort4*)(o + ((size_t)(b * 256 + i) * 128 + hh * 16 + d0)) = *(ushort4*)p4;
}

// ---------------------------------------------------------------------------
extern "C" void kernel_launch(void* const* d_in, const int* in_sizes, int n_in,
                              void* d_out, int out_size, void* d_ws, size_t ws_size,
                              hipStream_t stream) {
  const float* input_x = (const float*)d_in[0];
  const float* edge_attr = (const float*)d_in[1];
  const float* gcn_lin_w = (const float*)d_in[2];
  const float* gcn_root = (const float*)d_in[3];
  const float* gcn_edge_w = (const float*)d_in[4];
  const float* gcn_ng = (const float*)d_in[5];
  const float* gcn_nb = (const float*)d_in[6];
  const float* ln_in_g = (const float*)d_in[7];
  const float* ln_in_b = (const float*)d_in[8];
  const float* ln_ffn_g = (const float*)d_in[9];
  const float* ln_ffn_b = (const float*)d_in[10];
  const float* mcl_w = (const float*)d_in[11];
  const float* q_w = (const float*)d_in[12];
  const float* k_w = (const float*)d_in[13];
  const float* v_w = (const float*)d_in[14];
  const float* merge_w = (const float*)d_in[15];
  const float* merge_b = (const float*)d_in[16];
  const float* ffn_w1 = (const float*)d_in[17];
  const float* ffn_b1 = (const float*)d_in[18];
  const float* ffn_w2 = (const float*)d_in[19];
  const float* ffn_b2 = (const float*)d_in[20];
  const float* final_g = (const float*)d_in[21];
  const float* final_b = (const float*)d_in[22];
  const int* edge_index = (const int*)d_in[23];
  const int* n_counts = (const int*)d_in[24];
  const int* root = (const int*)d_in[25];

  const int E = in_sizes[23] / 2;
  const int B = in_sizes[24];
  const int BN = B * NNODE;

  float* ws = (float*)d_ws;
  size_t off = 0;
  auto alloc = [&](size_t n) {
    off = (off + 3) & ~(size_t)3;  // 16B alignment
    float* p = ws + off;
    off += n;
    return p;
  };
  const size_t NN2 = (size_t)B * 256 * 256;
  const size_t XF = (size_t)BN * 128;
  float* mclr = alloc(NN2);   // mclT fp32 (persists)
  float* mbuf = alloc(NN2);   // adj/m; later qkv (spans into rt)
  float* rt = alloc(NN2);     // qkv tail, f2 etc.
  float* hbuf = alloc(XF);    // h (fp32)
  float* xbuf = alloc(XF);    // post-attn LN output (FFN residual)
  float* deg = alloc(BN);
  float* dis = alloc(BN);
  int* rowptr = (int*)alloc(BN + 1);
  int* ccount = (int*)alloc(BN);
  int* fill = (int*)alloc(BN);
  int* src_s = (int*)alloc(E);
  int* eidx_s = (int*)alloc(E);
  float* enorm_s = alloc(E);
  u16* mb16 = (u16*)alloc(NN2 / 2);
  u16* rT16 = (u16*)alloc(NN2 / 2);
  u16* cT16 = (u16*)alloc(NN2 / 2);
  u16* outb16 = (u16*)alloc(XF / 2);     // bf16 mirror of running act
  u16* xb16 = (u16*)alloc(XF / 2);       // bf16 mirror of xbuf
  u16* ob16 = (u16*)alloc(XF / 2);       // attn out bf16
  u16* f116 = (u16*)alloc(XF);           // ffn hidden bf16 (BN*256)
  // bf16 weights
  u16* wlin16 = (u16*)alloc((size_t)NLAYER * 128 * 128 / 2);
  u16* wq16 = (u16*)alloc((size_t)NLAYER * 128 * 128 / 2);
  u16* wk16 = (u16*)alloc((size_t)NLAYER * 128 * 128 / 2);
  u16* wv16 = (u16*)alloc((size_t)NLAYER * 128 * 128 / 2);
  u16* wm16 = (u16*)alloc((size_t)NLAYER * 128 * 128 / 2);
  u16* wf116 = (u16*)alloc((size_t)NLAYER * 256 * 128 / 2);
  u16* wf216 = (u16*)alloc((size_t)NLAYER * 128 * 256 / 2);

  float* qkv = mbuf;  // 3*XF <= 2*NN2
  float* om = mbuf;   // merge output (q/k/v dead)
  float* f2 = rt;     // ffn2 output
  float* outb = (float*)d_out;

  // ---- one-time: adjacency, degree, CSR, MCL, weight conversion ----
  hipMemsetAsync(mbuf, 0, NN2 * sizeof(float), stream);
  hipMemsetAsync(deg, 0, BN * sizeof(float), stream);
  hipMemsetAsync(ccount, 0, BN * sizeof(int), stream);
  hipMemsetAsync(fill, 0, BN * sizeof(int), stream);
  build_adj_kernel<<<(E + 255) / 256, 256, 0, stream>>>(edge_index, mbuf, deg, ccount, E);
  selfloop_deg_kernel<<<BN / 256, 256, 0, stream>>>(n_counts, mbuf, deg, dis);
  scan_kernel<<<1, 1024, 0, stream>>>(ccount, rowptr, BN);
  scatter_kernel<<<(E + 255) / 256, 256, 0, stream>>>(edge_index, dis, rowptr, fill, src_s,
                                                      eidx_s, enorm_s, E);
  dim3 cwg(72, 7);
  conv_w_kernel<<<cwg, 256, 0, stream>>>(gcn_lin_w, q_w, k_w, v_w, merge_w, ffn_w1, ffn_w2,
                                         wlin16, wq16, wk16, wv16, wm16, wf116, wf216);
  norm_rows_kernel<<<BN, 256, 0, stream>>>(mbuf, mbuf);
  dim3 mmg(4, 4, B);
  mcl_prep_kernel<<<mmg, 256, 0, stream>>>(mbuf, mb16, rT16);
  for (int it = 0; it < 6; it++) {
    mcl_mfma_kernel<<<mmg, 256, 0, stream>>>(rT16, mb16, cT16);
    int inflate = (it == 2 || it == 5) ? 1 : 0;
    mcl_norm_kernel<<<B * 4, 256, 0, stream>>>(cT16, rT16, mclr, inflate, it == 5 ? 1 : 0);
  }

  copy_x_kernel<<<XF / 256, 256, 0, stream>>>(input_x, outb, outb16);

  dim3 g4(BN / 64, 4), g8(BN / 64, 8), g12(BN / 64, 12);
  dim3 ag(4, NHEAD, B);
  for (int l = 0; l < NLAYER; l++) {
    // GCN
    mfma_nt_kernel<128, 0, 0><<<g4, 256, 0, stream>>>(
        outb16, wlin16 + (size_t)l * 128 * 128, nullptr, hbuf, nullptr, 128, 1.0f);
    gcn_fused_kernel<<<BN / 4, 256, 0, stream>>>(
        rowptr, src_s, eidx_s, enorm_s, edge_attr, gcn_edge_w + (size_t)l * 128 * 7, hbuf,
        gcn_root + (size_t)l * 2 * 128, root, deg, gcn_ng + l * 128, gcn_nb + l * 128, outb,
        outb16);
    // attention
    mfma_qkv_kernel<<<g12, 256, 0, stream>>>(outb16, wq16 + (size_t)l * 128 * 128,
                                             wk16 + (size_t)l * 128 * 128,
                                             wv16 + (size_t)l * 128 * 128, qkv, BN);
    attn4_kernel<<<ag, 256, 0, stream>>>(qkv, qkv + XF, qkv + 2 * XF, mclr,
                                         mcl_w + l * NHEAD, n_counts, ob16);
    mfma_nt_kernel<128, 1, 0><<<g4, 256, 0, stream>>>(
        ob16, wm16 + (size_t)l * 128 * 128, merge_b + l * 128, om, nullptr, 128, 1.0f);
    ln_add_kernel<<<BN / 4, 256, 0, stream>>>(om, outb, ln_in_g + l * 128, ln_in_b + l * 128,
                                              xbuf, xb16);
    // FFN
    mfma_nt_kernel<128, 2, 1><<<g8, 256, 0, stream>>>(
        xb16, wf116 + (size_t)l * 256 * 128, ffn_b1 + l * 256, nullptr, f116, 256, 1.0f);
    mfma_nt_kernel<256, 1, 0><<<g4, 256, 0, stream>>>(
        f116, wf216 + (size_t)l * 128 * 256, ffn_b2 + l * 128, f2, nullptr, 128, 1.0f);
    ln_add_kernel<<<BN / 4, 256, 0, stream>>>(f2, xbuf, ln_ffn_g + l * 128,
                                              ln_ffn_b + l * 128, outb, outb16);
  }
  // final layernorm (in place on d_out)
  ln_add_kernel<<<BN / 4, 256, 0, stream>>>(outb, nullptr, final_g, final_b, outb, nullptr);
}